// Round 11
// baseline (211.928 us; speedup 1.0000x reference)
//
#include <hip/hip_runtime.h>

// Loss = mean(0.5*(o-t)^2 * ef(t)) over N = 64*1*512*512 = 2^24 fp32 elements.
// ef(t) = BETA - exp((A-1)*ln(x) - x + BIAS),  x = (t - LOC)/SCALE
// FINAL path model (16 experiments, 2 sessions):
//   IF$->CU reads ~3.0 TB/s cap (R15: FETCH~0, all-IF$-hit, 2.96 measured).
//   HBM-NT reads ~3.7. Mixed one-stream-each ~4.3 combined (R7/R16,
//   main ~30-40us vs 30us floor). Rebalance null (R11), MLP/occupancy null
//   (R1-R5), DMA-to-LDS regresses (R13), all-IF$ regresses (R15), monolithic
//   asm regresses (R8/R9). NT probes+hits IF$ when resident (R15), so out
//   must be kept OUT of IF$ (never read cached) to use the HBM-NT path.
// R17: keep R16's optimal read config (out=NT builtin, tgt=cached) and
// remove the LAST remaining overhead we control: the finalize DISPATCH.
// Last-block-done pattern (device-global ticket + __threadfence; rocPRIM
// idiom): block drawing ticket NBLOCKS-1 is provably last -> sums partials
// in-kernel with the IDENTICAL reduction order as the old finalize kernel
// (bit-identical result), then resets the ticket (race-free: all adds done)
// -> graph-replay-safe, no memset. Saves one dispatch gap + 1-block kernel.
// Predict wall 133.2 -> ~127-131. Pre-commit: <=2us gain or regression =>
// declare <<ROOFLINE>> (fills + read-cap floor + launch overhead is all
// that remains).
// R18 = R17 resubmitted verbatim (GPU acquisition timeout, never measured).

#define NBLOCKS 2048
#define NTHREADS 256
#define F4_PER_THREAD 8   // 2048*256*8*4 = 2^24 elements exactly

typedef float vf4 __attribute__((ext_vector_type(4)));

// Ticket counter for last-block-done. Module .data: persists across graph
// replays; self-resetting (last block zeroes it after all adds completed).
__device__ int g_ticket = 0;

__device__ __forceinline__ float ef_term(float o, float y) {
    constexpr float A_M1      = -0.93555708575356741f;  // EST_A - 1
    constexpr float NEG_LOC   =  1.1328205299926424e-27f;
    constexpr float INV_SCALE =  0.65034886603218541f;  // 1/1.5376362609160314
    constexpr float BIAS      = -56.8416699f;
    constexpr float BETA      =  5.0f;

    float x  = (y + NEG_LOC) * INV_SCALE;           // > 0 for y >= 0
    float ex = __expf(fmaf(A_M1, __logf(x), BIAS - x));
    float ef = BETA - ex;                            // == c when y == 0
    float d  = o - y;
    return 0.5f * d * d * ef;
}

__device__ __forceinline__ vf4 ld_nt(const vf4* p) {
    return __builtin_nontemporal_load(p);
}

__device__ __forceinline__ float block_reduce(float acc) {
    #pragma unroll
    for (int off = 32; off > 0; off >>= 1)
        acc += __shfl_down(acc, off, 64);
    __shared__ float wsum[NTHREADS / 64];
    int lane = threadIdx.x & 63;
    int wave = threadIdx.x >> 6;
    if (lane == 0) wsum[wave] = acc;
    __syncthreads();
    float s = 0.f;
    if (threadIdx.x == 0) {
        #pragma unroll
        for (int w = 0; w < NTHREADS / 64; ++w) s += wsum[w];
    }
    return s;  // valid on thread 0 only
}

// Fast path: n == NBLOCKS*NTHREADS*F4_PER_THREAD*4 exactly.
// Round r fully coalesced: float4 index = chunk_base + r*NTHREADS + tid.
// out: NT (HBM stream, never IF$). tgt: cached (IF$-resident steady state).
// Finalize fused: last finished block sums partials and writes result.
__global__ __launch_bounds__(NTHREADS, 2) void ef_loss_partial_fast(
    const float* __restrict__ out, const float* __restrict__ tgt,
    float* __restrict__ partials, float* __restrict__ result) {
    const int base = blockIdx.x * (NTHREADS * F4_PER_THREAD) + threadIdx.x;
    const vf4* __restrict__ op = (const vf4*)out;
    const vf4* __restrict__ tp = (const vf4*)tgt;

    vf4 o0  = ld_nt(op + base + 0 * NTHREADS);
    vf4 o1  = ld_nt(op + base + 1 * NTHREADS);
    vf4 o2  = ld_nt(op + base + 2 * NTHREADS);
    vf4 o3  = ld_nt(op + base + 3 * NTHREADS);
    vf4 o4v = ld_nt(op + base + 4 * NTHREADS);
    vf4 o5  = ld_nt(op + base + 5 * NTHREADS);
    vf4 o6  = ld_nt(op + base + 6 * NTHREADS);
    vf4 o7  = ld_nt(op + base + 7 * NTHREADS);

    vf4 t0  = tp[base + 0 * NTHREADS];
    vf4 t1  = tp[base + 1 * NTHREADS];
    vf4 t2  = tp[base + 2 * NTHREADS];
    vf4 t3  = tp[base + 3 * NTHREADS];
    vf4 t4v = tp[base + 4 * NTHREADS];
    vf4 t5  = tp[base + 5 * NTHREADS];
    vf4 t6  = tp[base + 6 * NTHREADS];
    vf4 t7  = tp[base + 7 * NTHREADS];

    float a0 = 0.f, a1 = 0.f, a2 = 0.f, a3 = 0.f;

#define EF_ROUND(ov, tv)                                                    \
    do {                                                                    \
        a0 += ef_term(ov.x, tv.x);                                          \
        a1 += ef_term(ov.y, tv.y);                                          \
        a2 += ef_term(ov.z, tv.z);                                          \
        a3 += ef_term(ov.w, tv.w);                                          \
    } while (0)

    EF_ROUND(o0, t0);
    EF_ROUND(o1, t1);
    EF_ROUND(o2, t2);
    EF_ROUND(o3, t3);
    EF_ROUND(o4v, t4v);
    EF_ROUND(o5, t5);
    EF_ROUND(o6, t6);
    EF_ROUND(o7, t7);
#undef EF_ROUND

    float s = block_reduce((a0 + a1) + (a2 + a3));

    __shared__ bool amLast;
    if (threadIdx.x == 0) {
        partials[blockIdx.x] = s;
        __threadfence();                       // make partials visible device-wide
        int t = atomicAdd(&g_ticket, 1);       // device-scope atomic
        amLast = (t == NBLOCKS - 1);
    }
    __syncthreads();

    if (amLast) {                              // uniform across the block
        __threadfence();                       // order: see all partials stores
        float acc = 0.f;
        for (int i = threadIdx.x; i < NBLOCKS; i += NTHREADS)
            acc += partials[i];                // same order as old finalize kernel
        float tot = block_reduce(acc);
        if (threadIdx.x == 0) {
            constexpr float INV_N =
                1.0f / (float)(NBLOCKS * NTHREADS * F4_PER_THREAD * 4);
            result[0] = tot * INV_N;
            g_ticket = 0;                      // all adds done -> race-free reset
        }
    }
}

// Generic fallback (any n): two-kernel structure.
__global__ __launch_bounds__(NTHREADS) void ef_loss_partial_gen(
    const float* __restrict__ out, const float* __restrict__ tgt,
    float* __restrict__ partials, int n) {
    const int idx    = blockIdx.x * blockDim.x + threadIdx.x;
    const int stride = gridDim.x * blockDim.x;
    const int n4     = n >> 2;
    const float4* __restrict__ o4 = (const float4*)out;
    const float4* __restrict__ t4 = (const float4*)tgt;

    float acc = 0.f;
    for (int i = idx; i < n4; i += stride) {
        float4 o = o4[i];
        float4 t = t4[i];
        acc += ef_term(o.x, t.x);
        acc += ef_term(o.y, t.y);
        acc += ef_term(o.z, t.z);
        acc += ef_term(o.w, t.w);
    }
    for (int i = (n4 << 2) + idx; i < n; i += stride)
        acc += ef_term(out[i], tgt[i]);

    float s = block_reduce(acc);
    if (threadIdx.x == 0) partials[blockIdx.x] = s;
}

__global__ __launch_bounds__(NTHREADS) void ef_loss_finalize(
    const float* __restrict__ partials, float* __restrict__ result,
    int nblocks, float inv_n) {
    float acc = 0.f;
    for (int i = threadIdx.x; i < nblocks; i += blockDim.x)
        acc += partials[i];
    float s = block_reduce(acc);
    if (threadIdx.x == 0) result[0] = s * inv_n;
}

extern "C" void kernel_launch(void* const* d_in, const int* in_sizes, int n_in,
                              void* d_out, int out_size, void* d_ws, size_t ws_size,
                              hipStream_t stream) {
    const float* out_p = (const float*)d_in[0];   // "output"
    const float* tgt_p = (const float*)d_in[1];   // "target"
    float* partials = (float*)d_ws;               // NBLOCKS floats = 8 KB
    float* result   = (float*)d_out;
    const int n = in_sizes[0];

    if (n == NBLOCKS * NTHREADS * F4_PER_THREAD * 4) {
        ef_loss_partial_fast<<<NBLOCKS, NTHREADS, 0, stream>>>(out_p, tgt_p,
                                                               partials, result);
    } else {
        ef_loss_partial_gen<<<NBLOCKS, NTHREADS, 0, stream>>>(out_p, tgt_p,
                                                              partials, n);
        ef_loss_finalize<<<1, NTHREADS, 0, stream>>>(partials, result, NBLOCKS,
                                                     1.0f / (float)n);
    }
}

// Round 12
// 132.910 us; speedup vs baseline: 1.5945x; 1.5945x over previous
//
#include <hip/hip_runtime.h>

// Loss = mean(0.5*(o-t)^2 * ef(t)) over N = 64*1*512*512 = 2^24 fp32 elements.
// ef(t) = BETA - exp((A-1)*ln(x) - x + BIAS),  x = (t - LOC)/SCALE
// FINAL path model (17 experiments, 2 sessions):
//   IF$->CU reads ~3.0 TB/s cap (R15: FETCH~0, all-IF$-hit, 2.96 measured).
//   HBM-NT reads ~3.7 (R6). Mixed one-stream-each ~4.3 combined (R7/R16,
//   main ~30-40us vs 30us floor = 128MiB/4.3TB/s). Null/regression results:
//   rebalance (R11), MLP/occupancy (R1-R5), DMA-to-LDS (R13), all-IF$ via
//   warming (R15: NT probes+hits IF$ when resident -> out must stay OUT of
//   IF$), monolithic asm (R8/R9), fused finalize via ticket+__threadfence
//   (R17: threadfence = device-scope release = L2 writeback x2048 blocks ->
//   main 110-131us, catastrophic; dispatch-boundary ordering is free).
// R19 = R16 restored verbatim: out = builtin NT loads (HBM stream), tgt =
// plain cached loads (IF$-resident), (256,2), two-kernel structure.
// This is the structural optimum: mandatory 128 MiB reads / measured
// ~4.3 TB/s chip mixed-read cap. Declaring roofline if it reproduces.

#define NBLOCKS 2048
#define NTHREADS 256
#define F4_PER_THREAD 8   // 2048*256*8*4 = 2^24 elements exactly

typedef float vf4 __attribute__((ext_vector_type(4)));

__device__ __forceinline__ float ef_term(float o, float y) {
    constexpr float A_M1      = -0.93555708575356741f;  // EST_A - 1
    constexpr float NEG_LOC   =  1.1328205299926424e-27f;
    constexpr float INV_SCALE =  0.65034886603218541f;  // 1/1.5376362609160314
    constexpr float BIAS      = -56.8416699f;
    constexpr float BETA      =  5.0f;

    float x  = (y + NEG_LOC) * INV_SCALE;           // > 0 for y >= 0
    float ex = __expf(fmaf(A_M1, __logf(x), BIAS - x));
    float ef = BETA - ex;                            // == c when y == 0
    float d  = o - y;
    return 0.5f * d * d * ef;
}

__device__ __forceinline__ vf4 ld_nt(const vf4* p) {
    return __builtin_nontemporal_load(p);
}

__device__ __forceinline__ float block_reduce(float acc) {
    #pragma unroll
    for (int off = 32; off > 0; off >>= 1)
        acc += __shfl_down(acc, off, 64);
    __shared__ float wsum[NTHREADS / 64];
    int lane = threadIdx.x & 63;
    int wave = threadIdx.x >> 6;
    if (lane == 0) wsum[wave] = acc;
    __syncthreads();
    float s = 0.f;
    if (threadIdx.x == 0) {
        #pragma unroll
        for (int w = 0; w < NTHREADS / 64; ++w) s += wsum[w];
    }
    return s;  // valid on thread 0 only
}

// Fast path: n == NBLOCKS*NTHREADS*F4_PER_THREAD*4 exactly.
// Round r fully coalesced: float4 index = chunk_base + r*NTHREADS + tid.
// out: NT (HBM stream, never IF$). tgt: cached (IF$-resident steady state).
__global__ __launch_bounds__(NTHREADS, 2) void ef_loss_partial_fast(
    const float* __restrict__ out, const float* __restrict__ tgt,
    float* __restrict__ partials) {
    const int base = blockIdx.x * (NTHREADS * F4_PER_THREAD) + threadIdx.x;
    const vf4* __restrict__ op = (const vf4*)out;
    const vf4* __restrict__ tp = (const vf4*)tgt;

    vf4 o0  = ld_nt(op + base + 0 * NTHREADS);
    vf4 o1  = ld_nt(op + base + 1 * NTHREADS);
    vf4 o2  = ld_nt(op + base + 2 * NTHREADS);
    vf4 o3  = ld_nt(op + base + 3 * NTHREADS);
    vf4 o4v = ld_nt(op + base + 4 * NTHREADS);
    vf4 o5  = ld_nt(op + base + 5 * NTHREADS);
    vf4 o6  = ld_nt(op + base + 6 * NTHREADS);
    vf4 o7  = ld_nt(op + base + 7 * NTHREADS);

    vf4 t0  = tp[base + 0 * NTHREADS];
    vf4 t1  = tp[base + 1 * NTHREADS];
    vf4 t2  = tp[base + 2 * NTHREADS];
    vf4 t3  = tp[base + 3 * NTHREADS];
    vf4 t4v = tp[base + 4 * NTHREADS];
    vf4 t5  = tp[base + 5 * NTHREADS];
    vf4 t6  = tp[base + 6 * NTHREADS];
    vf4 t7  = tp[base + 7 * NTHREADS];

    float a0 = 0.f, a1 = 0.f, a2 = 0.f, a3 = 0.f;

#define EF_ROUND(ov, tv)                                                    \
    do {                                                                    \
        a0 += ef_term(ov.x, tv.x);                                          \
        a1 += ef_term(ov.y, tv.y);                                          \
        a2 += ef_term(ov.z, tv.z);                                          \
        a3 += ef_term(ov.w, tv.w);                                          \
    } while (0)

    EF_ROUND(o0, t0);
    EF_ROUND(o1, t1);
    EF_ROUND(o2, t2);
    EF_ROUND(o3, t3);
    EF_ROUND(o4v, t4v);
    EF_ROUND(o5, t5);
    EF_ROUND(o6, t6);
    EF_ROUND(o7, t7);
#undef EF_ROUND

    float s = block_reduce((a0 + a1) + (a2 + a3));
    if (threadIdx.x == 0) partials[blockIdx.x] = s;
}

// Generic fallback (any n).
__global__ __launch_bounds__(NTHREADS) void ef_loss_partial_gen(
    const float* __restrict__ out, const float* __restrict__ tgt,
    float* __restrict__ partials, int n) {
    const int idx    = blockIdx.x * blockDim.x + threadIdx.x;
    const int stride = gridDim.x * blockDim.x;
    const int n4     = n >> 2;
    const float4* __restrict__ o4 = (const float4*)out;
    const float4* __restrict__ t4 = (const float4*)tgt;

    float acc = 0.f;
    for (int i = idx; i < n4; i += stride) {
        float4 o = o4[i];
        float4 t = t4[i];
        acc += ef_term(o.x, t.x);
        acc += ef_term(o.y, t.y);
        acc += ef_term(o.z, t.z);
        acc += ef_term(o.w, t.w);
    }
    for (int i = (n4 << 2) + idx; i < n; i += stride)
        acc += ef_term(out[i], tgt[i]);

    float s = block_reduce(acc);
    if (threadIdx.x == 0) partials[blockIdx.x] = s;
}

__global__ __launch_bounds__(NTHREADS) void ef_loss_finalize(
    const float* __restrict__ partials, float* __restrict__ result,
    int nblocks, float inv_n) {
    float acc = 0.f;
    for (int i = threadIdx.x; i < nblocks; i += blockDim.x)
        acc += partials[i];
    float s = block_reduce(acc);
    if (threadIdx.x == 0) result[0] = s * inv_n;
}

extern "C" void kernel_launch(void* const* d_in, const int* in_sizes, int n_in,
                              void* d_out, int out_size, void* d_ws, size_t ws_size,
                              hipStream_t stream) {
    const float* out_p = (const float*)d_in[0];   // "output"
    const float* tgt_p = (const float*)d_in[1];   // "target"
    float* partials = (float*)d_ws;               // NBLOCKS floats = 8 KB
    float* result   = (float*)d_out;
    const int n = in_sizes[0];

    if (n == NBLOCKS * NTHREADS * F4_PER_THREAD * 4) {
        ef_loss_partial_fast<<<NBLOCKS, NTHREADS, 0, stream>>>(out_p, tgt_p, partials);
    } else {
        ef_loss_partial_gen<<<NBLOCKS, NTHREADS, 0, stream>>>(out_p, tgt_p, partials, n);
    }
    ef_loss_finalize<<<1, NTHREADS, 0, stream>>>(partials, result, NBLOCKS,
                                                 1.0f / (float)n);
}